// Round 4
// baseline (259.721 us; speedup 1.0000x reference)
//
#include <hip/hip_runtime.h>

#define MAXIT  100
#define R0     10      // round-0 iterations (from global)
#define RSTEP  10      // iterations per LDS-compacted round
#define TARGET 30.0f
#define WEIGHT 0.1f
#define EPS    1e-6f
#define EPB    1024    // elements per block
#define TPB    256

// One branchless Mandelbrot step. Matches reference semantics exactly:
// z always updates; iters ("fin") and active latch via selects; cycle wins
// over escape in the same iteration. Dead lanes keep iterating harmlessly
// (inf/nan cannot re-trigger: alive is already false).
__device__ __forceinline__ void iter_step(float& zr, float& zi, float c_r, float c_i,
                                          float& fin, bool& alive, float fi) {
  float zr_new = __builtin_fmaf(zr, zr, c_r - zi * zi);
  float zi_new = __builtin_fmaf(zr + zr, zi, c_i);
  bool cyc = (fabsf(zr_new - zr) < EPS) & (fabsf(zi_new - zi) < EPS) & alive;
  bool esc = (__builtin_fmaf(zr_new, zr_new, zi_new * zi_new) > 4.0f) & alive & (!cyc);
  fin = cyc ? 100.0f : fin;
  fin = esc ? fi : fin;
  alive = alive & (!cyc) & (!esc);
  zr = zr_new; zi = zi_new;
}

__global__ __launch_bounds__(TPB) void escape_partial(
    const float* __restrict__ crg, const float* __restrict__ cig,
    float* __restrict__ partial, int n) {
  __shared__ float4 q[EPB];
  __shared__ int scount;
  __shared__ float sm[4];

  const int tid  = threadIdx.x;
  const int lane = tid & 63;
  const int wid  = tid >> 6;
  const int blockBase = blockIdx.x * EPB;

  float nd = 0.0f;
  float eZr[4], eZi[4], eCr[4], eCi[4];
  bool  eAl[4];

  // ---- round 0: iters [0, R0), source = global, float4 loads ----
  const bool fullBlock = (blockBase + EPB) <= n;
  float4 vcr, vci;
  if (fullBlock) {
    vcr = reinterpret_cast<const float4*>(crg + blockBase)[tid];
    vci = reinterpret_cast<const float4*>(cig + blockBase)[tid];
  } else {
    int b = blockBase + 4 * tid;
    vcr.x = (b + 0 < n) ? crg[b + 0] : 9.0f;  vci.x = (b + 0 < n) ? cig[b + 0] : 9.0f;
    vcr.y = (b + 1 < n) ? crg[b + 1] : 9.0f;  vci.y = (b + 1 < n) ? cig[b + 1] : 9.0f;
    vcr.z = (b + 2 < n) ? crg[b + 2] : 9.0f;  vci.z = (b + 2 < n) ? cig[b + 2] : 9.0f;
    vcr.w = (b + 3 < n) ? crg[b + 3] : 9.0f;  vci.w = (b + 3 < n) ? cig[b + 3] : 9.0f;
  }
  const float crs[4] = {vcr.x, vcr.y, vcr.z, vcr.w};
  const float cis[4] = {vci.x, vci.y, vci.z, vci.w};
  const bool  vld[4] = {
    fullBlock || (blockBase + 4 * tid + 0 < n),
    fullBlock || (blockBase + 4 * tid + 1 < n),
    fullBlock || (blockBase + 4 * tid + 2 < n),
    fullBlock || (blockBase + 4 * tid + 3 < n)};

  #pragma unroll
  for (int k = 0; k < 4; ++k) {
    float c_r = crs[k], c_i = cis[k];
    // i = 0 peeled: z1 = c, no cycle check (reference: i > 0)
    float zr = c_r, zi = c_i;
    bool alive = vld[k];
    float fin = 0.0f;
    bool esc0 = (__builtin_fmaf(c_r, c_r, c_i * c_i) > 4.0f) & alive;
    fin = esc0 ? 1.0f : fin;
    alive = alive & (!esc0);
    float fi = 2.0f;
    #pragma unroll
    for (int i = 1; i < R0; ++i) { iter_step(zr, zi, c_r, c_i, fin, alive, fi); fi += 1.0f; }
    if (fin != 0.0f) nd += fabsf(fin - TARGET) * (1.0f / TARGET);
    eAl[k] = alive; eZr[k] = zr; eZi[k] = zi; eCr[k] = c_r; eCi[k] = c_i;
  }

  if (tid == 0) scount = 0;
  __syncthreads();
  #pragma unroll
  for (int k = 0; k < 4; ++k) {            // ballot-compact append into LDS queue
    unsigned long long bal = __ballot(eAl[k]);
    int cnt = __popcll(bal);
    if (cnt) {
      int wbase = 0;
      if (lane == 0) wbase = atomicAdd(&scount, cnt);
      wbase = __shfl(wbase, 0, 64);
      if (eAl[k]) {
        int pos = wbase + __popcll(bal & ((1ull << lane) - 1ull));
        q[pos] = make_float4(eZr[k], eZi[k], eCr[k], eCi[k]);
      }
    }
  }
  __syncthreads();
  int S = scount;
  int rot = 0;

  // ---- LDS-compacted rounds: iters [base, base+RSTEP) ----
  for (int base = R0; base < MAXIT && S > 0; base += RSTEP) {
    rot = (rot + 64) & (TPB - 1);          // rotate partial-wave tail across SIMDs
    const int effTid = (tid + rot) & (TPB - 1);
    #pragma unroll
    for (int k = 0; k < 4; ++k) {
      eAl[k] = false;
      int j = k * TPB + effTid;
      if (j < S) {
        float4 e = q[j];
        float zr = e.x, zi = e.y, c_r = e.z, c_i = e.w;
        bool alive = true;
        float fin = 0.0f;
        float fi = (float)(base + 1);
        #pragma unroll
        for (int i = 0; i < RSTEP; ++i) { iter_step(zr, zi, c_r, c_i, fin, alive, fi); fi += 1.0f; }
        if (fin != 0.0f) nd += fabsf(fin - TARGET) * (1.0f / TARGET);
        eAl[k] = alive; eZr[k] = zr; eZi[k] = zi; eCr[k] = c_r; eCi[k] = c_i;
      }
    }
    __syncthreads();                       // all queue reads done
    if (tid == 0) scount = 0;
    __syncthreads();
    #pragma unroll
    for (int k = 0; k < 4; ++k) {          // in-place re-compaction
      unsigned long long bal = __ballot(eAl[k]);
      int cnt = __popcll(bal);
      if (cnt) {
        int wbase = 0;
        if (lane == 0) wbase = atomicAdd(&scount, cnt);
        wbase = __shfl(wbase, 0, 64);
        if (eAl[k]) {
          int pos = wbase + __popcll(bal & ((1ull << lane) - 1ull));
          q[pos] = make_float4(eZr[k], eZi[k], eCr[k], eCi[k]);
        }
      }
    }
    __syncthreads();
    S = scount;
  }

  // ---- survivors after 100 iters: iters = 100 ----
  {
    int mine = 0;
    #pragma unroll
    for (int k = 0; k < 4; ++k) if (k * TPB + tid < S) ++mine;
    nd += (float)mine * ((100.0f - TARGET) * (1.0f / TARGET));
  }

  // ---- block reduce ----
  for (int off = 32; off > 0; off >>= 1) nd += __shfl_down(nd, off, 64);
  if (lane == 0) sm[wid] = nd;
  __syncthreads();
  if (tid == 0) partial[blockIdx.x] = sm[0] + sm[1] + sm[2] + sm[3];
}

// Single block: read all partials, write out[0] directly (no memset, no atomics).
__global__ __launch_bounds__(256) void reduce_final(
    const float* __restrict__ partial, int nparts,
    float* __restrict__ out, float scale) {
  float s = 0.0f;
  for (int i = threadIdx.x; i < nparts; i += 256) s += partial[i];
  for (int off = 32; off > 0; off >>= 1) s += __shfl_down(s, off, 64);
  __shared__ float sm[4];
  int lane = threadIdx.x & 63, wid = threadIdx.x >> 6;
  if (lane == 0) sm[wid] = s;
  __syncthreads();
  if (threadIdx.x == 0)
    out[0] = (sm[0] + sm[1] + sm[2] + sm[3]) * scale;
}

extern "C" void kernel_launch(void* const* d_in, const int* in_sizes, int n_in,
                              void* d_out, int out_size, void* d_ws, size_t ws_size,
                              hipStream_t stream) {
  const float* cr = (const float*)d_in[0];
  const float* ci = (const float*)d_in[1];
  int n = in_sizes[0];
  int blocks = (n + EPB - 1) / EPB;        // 8192 at N=8388608
  float* partial = (float*)d_ws;

  escape_partial<<<blocks, TPB, 0, stream>>>(cr, ci, partial, n);
  reduce_final<<<1, 256, 0, stream>>>(partial, blocks, (float*)d_out,
                                      WEIGHT / (float)n);
}

// Round 5
// 174.710 us; speedup vs baseline: 1.4866x; 1.4866x over previous
//
#include <hip/hip_runtime.h>

#define MAXIT  100
#define TARGET 30.0f
#define WEIGHT 0.1f
#define EPS    1e-6f
#define EPB    1024    // elements per block
#define TPB    256
#define R0     12      // phase-A iters (3 bodies of 4, from z=0)
#define RSTEP  12      // iters per queue round (3 bodies of 4)

// Four Mandelbrot iterations (finishing values fb+1..fb+4), ping-pong SSA.
// Escape compare per iteration; 1-step cycle check once at the 4th iteration
// (a converging orbit stays below EPS once it gets there, so detection is
// delayed <=3 iters but records the same value, 100). Cycle at iter fb+4
// wins over escape at fb+4 (reference order); earlier escapes win over it.
// Decode of the first-escape index runs only in the rare exit path.
__device__ __forceinline__ void body4(float& zr, float& zi, float cr, float ci,
                                      float fb, float& fin, bool& alive) {
  float t0  = __builtin_fmaf(-zi, zi, cr);
  float zr1 = __builtin_fmaf(zr, zr, t0);
  float zi1 = __builtin_fmaf(zr + zr, zi, ci);
  bool  e1  = __builtin_fmaf(zr1, zr1, zi1 * zi1) > 4.0f;

  float t1  = __builtin_fmaf(-zi1, zi1, cr);
  float zr2 = __builtin_fmaf(zr1, zr1, t1);
  float zi2 = __builtin_fmaf(zr1 + zr1, zi1, ci);
  bool  e2  = __builtin_fmaf(zr2, zr2, zi2 * zi2) > 4.0f;

  float t2  = __builtin_fmaf(-zi2, zi2, cr);
  float zr3 = __builtin_fmaf(zr2, zr2, t2);
  float zi3 = __builtin_fmaf(zr2 + zr2, zi2, ci);
  bool  e3  = __builtin_fmaf(zr3, zr3, zi3 * zi3) > 4.0f;

  float t3  = __builtin_fmaf(-zi3, zi3, cr);
  float zr4 = __builtin_fmaf(zr3, zr3, t3);
  float zi4 = __builtin_fmaf(zr3 + zr3, zi3, ci);
  bool  e4  = __builtin_fmaf(zr4, zr4, zi4 * zi4) > 4.0f;

  bool cyc = (fabsf(zr4 - zr3) < EPS) & (fabsf(zi4 - zi3) < EPS);
  zr = zr4; zi = zi4;

  if ((e1 | e2 | e3 | e4 | cyc) & alive) {   // rare path
    float f = 100.0f;                        // cycle-only default
    if (e4 & !cyc) f = fb + 4.0f;            // same-iter: cycle wins
    if (e3) f = fb + 3.0f;
    if (e2) f = fb + 2.0f;
    if (e1) f = fb + 1.0f;
    fin = fminf(f, 100.0f);                  // last-round overshoot clamp
    alive = false;
  }
}

__global__ __launch_bounds__(TPB) void escape_partial(
    const float* __restrict__ crg, const float* __restrict__ cig,
    float* __restrict__ partial, int n) {
  __shared__ float4 q[EPB];
  __shared__ int scount;
  __shared__ float sm[4];

  const int tid  = threadIdx.x;
  const int lane = tid & 63;
  const int wid  = tid >> 6;
  const int blockBase = blockIdx.x * EPB;

  float nd = 0.0f;
  float eZr[4], eZi[4], eCr[4], eCi[4];
  bool  eAl[4];

  // ---- phase A: iters 1..R0 from z=0, float4 global loads ----
  const bool fullBlock = (blockBase + EPB) <= n;
  float4 vcr, vci;
  if (fullBlock) {
    vcr = reinterpret_cast<const float4*>(crg + blockBase)[tid];
    vci = reinterpret_cast<const float4*>(cig + blockBase)[tid];
  } else {
    int b = blockBase + 4 * tid;
    vcr.x = (b + 0 < n) ? crg[b + 0] : 9.0f;  vci.x = (b + 0 < n) ? cig[b + 0] : 9.0f;
    vcr.y = (b + 1 < n) ? crg[b + 1] : 9.0f;  vci.y = (b + 1 < n) ? cig[b + 1] : 9.0f;
    vcr.z = (b + 2 < n) ? crg[b + 2] : 9.0f;  vci.z = (b + 2 < n) ? cig[b + 2] : 9.0f;
    vcr.w = (b + 3 < n) ? crg[b + 3] : 9.0f;  vci.w = (b + 3 < n) ? cig[b + 3] : 9.0f;
  }
  const float crs[4] = {vcr.x, vcr.y, vcr.z, vcr.w};
  const float cis[4] = {vci.x, vci.y, vci.z, vci.w};
  const bool  vld[4] = {
    fullBlock || (blockBase + 4 * tid + 0 < n),
    fullBlock || (blockBase + 4 * tid + 1 < n),
    fullBlock || (blockBase + 4 * tid + 2 < n),
    fullBlock || (blockBase + 4 * tid + 3 < n)};

  #pragma unroll
  for (int k = 0; k < 4; ++k) {
    float c_r = crs[k], c_i = cis[k];
    float zr = 0.0f, zi = 0.0f;       // body4 from z=0 reproduces z1=c, e1=|c|^2>4
    float fin = 0.0f;
    bool alive = vld[k];
    body4(zr, zi, c_r, c_i, 0.0f, fin, alive);
    body4(zr, zi, c_r, c_i, 4.0f, fin, alive);
    body4(zr, zi, c_r, c_i, 8.0f, fin, alive);
    if (fin != 0.0f) nd += fabsf(fin - TARGET) * (1.0f / TARGET);
    eAl[k] = alive; eZr[k] = zr; eZi[k] = zi; eCr[k] = c_r; eCi[k] = c_i;
  }

  if (tid == 0) scount = 0;
  __syncthreads();
  #pragma unroll
  for (int k = 0; k < 4; ++k) {            // ballot-compact append into LDS queue
    unsigned long long bal = __ballot(eAl[k]);
    int cnt = __popcll(bal);
    if (cnt) {
      int wbase = 0;
      if (lane == 0) wbase = atomicAdd(&scount, cnt);
      wbase = __shfl(wbase, 0, 64);
      if (eAl[k]) {
        int pos = wbase + __popcll(bal & ((1ull << lane) - 1ull));
        q[pos] = make_float4(eZr[k], eZi[k], eCr[k], eCi[k]);
      }
    }
  }
  __syncthreads();
  int S = scount;
  int rot = 0;

  // ---- queue rounds: base = 12,24,...,96 (last overshoots to 108; clamped) ----
  for (int base = R0; base < MAXIT && S > 0; base += RSTEP) {
    rot = (rot + 64) & (TPB - 1);          // rotate partial-wave tail across SIMDs
    const int effTid = (tid + rot) & (TPB - 1);
    const float fb = (float)base;
    #pragma unroll
    for (int k = 0; k < 4; ++k) {
      eAl[k] = false;
      int j = k * TPB + effTid;
      if (j < S) {
        float4 e = q[j];
        float zr = e.x, zi = e.y, c_r = e.z, c_i = e.w;
        float fin = 0.0f;
        bool alive = true;
        body4(zr, zi, c_r, c_i, fb, fin, alive);
        body4(zr, zi, c_r, c_i, fb + 4.0f, fin, alive);
        body4(zr, zi, c_r, c_i, fb + 8.0f, fin, alive);
        if (fin != 0.0f) nd += fabsf(fin - TARGET) * (1.0f / TARGET);
        eAl[k] = alive; eZr[k] = zr; eZi[k] = zi; eCr[k] = c_r; eCi[k] = c_i;
      }
    }
    __syncthreads();                       // all queue reads done
    if (tid == 0) scount = 0;
    __syncthreads();
    #pragma unroll
    for (int k = 0; k < 4; ++k) {          // in-place re-compaction
      unsigned long long bal = __ballot(eAl[k]);
      int cnt = __popcll(bal);
      if (cnt) {
        int wbase = 0;
        if (lane == 0) wbase = atomicAdd(&scount, cnt);
        wbase = __shfl(wbase, 0, 64);
        if (eAl[k]) {
          int pos = wbase + __popcll(bal & ((1ull << lane) - 1ull));
          q[pos] = make_float4(eZr[k], eZi[k], eCr[k], eCi[k]);
        }
      }
    }
    __syncthreads();
    S = scount;
  }

  // ---- survivors (ran to >=100 without escape/cycle): iters = 100 ----
  {
    int mine = 0;
    #pragma unroll
    for (int k = 0; k < 4; ++k) if (k * TPB + tid < S) ++mine;
    nd += (float)mine * ((100.0f - TARGET) * (1.0f / TARGET));
  }

  // ---- block reduce ----
  for (int off = 32; off > 0; off >>= 1) nd += __shfl_down(nd, off, 64);
  if (lane == 0) sm[wid] = nd;
  __syncthreads();
  if (tid == 0) partial[blockIdx.x] = sm[0] + sm[1] + sm[2] + sm[3];
}

// Single block, float4 reads of the partials.
__global__ __launch_bounds__(256) void reduce_final(
    const float* __restrict__ partial, int nparts,
    float* __restrict__ out, float scale) {
  float s = 0.0f;
  int n4 = nparts >> 2;
  const float4* p4 = reinterpret_cast<const float4*>(partial);
  for (int i = threadIdx.x; i < n4; i += 256) {
    float4 v = p4[i];
    s += (v.x + v.y) + (v.z + v.w);
  }
  for (int i = (n4 << 2) + threadIdx.x; i < nparts; i += 256) s += partial[i];
  for (int off = 32; off > 0; off >>= 1) s += __shfl_down(s, off, 64);
  __shared__ float sm[4];
  int lane = threadIdx.x & 63, wid = threadIdx.x >> 6;
  if (lane == 0) sm[wid] = s;
  __syncthreads();
  if (threadIdx.x == 0)
    out[0] = (sm[0] + sm[1] + sm[2] + sm[3]) * scale;
}

extern "C" void kernel_launch(void* const* d_in, const int* in_sizes, int n_in,
                              void* d_out, int out_size, void* d_ws, size_t ws_size,
                              hipStream_t stream) {
  const float* cr = (const float*)d_in[0];
  const float* ci = (const float*)d_in[1];
  int n = in_sizes[0];
  int blocks = (n + EPB - 1) / EPB;        // 8192 at N=8388608
  float* partial = (float*)d_ws;

  escape_partial<<<blocks, TPB, 0, stream>>>(cr, ci, partial, n);
  reduce_final<<<1, 256, 0, stream>>>(partial, blocks, (float*)d_out,
                                      WEIGHT / (float)n);
}

// Round 6
// 155.789 us; speedup vs baseline: 1.6671x; 1.1215x over previous
//
#include <hip/hip_runtime.h>

#define MAXIT  100
#define TARGET 30.0f
#define WEIGHT 0.1f
#define EPS    1e-6f
#define EPB    1024    // elements per block
#define TPB    256
#define R0     12      // phase-A iters (3 bodies of 4, from z=0)
#define RSTEP  12      // iters per queue round (3 bodies of 4)
#define ND_INSET ((100.0f - TARGET) * (1.0f / TARGET))

// Four Mandelbrot iterations (finishing values fb+1..fb+4), ping-pong SSA.
// Escape compare per iteration; 1-step cycle check once at the 4th iteration
// (a converging orbit stays below EPS once it gets there, so detection is
// delayed <=3 iters but records the same value, 100). Cycle at iter fb+4
// wins over escape at fb+4 (reference order); earlier escapes win over it.
// Decode of the first-escape index runs only in the rare exit path.
__device__ __forceinline__ void body4(float& zr, float& zi, float cr, float ci,
                                      float fb, float& fin, bool& alive) {
  float t0  = __builtin_fmaf(-zi, zi, cr);
  float zr1 = __builtin_fmaf(zr, zr, t0);
  float zi1 = __builtin_fmaf(zr + zr, zi, ci);
  bool  e1  = __builtin_fmaf(zr1, zr1, zi1 * zi1) > 4.0f;

  float t1  = __builtin_fmaf(-zi1, zi1, cr);
  float zr2 = __builtin_fmaf(zr1, zr1, t1);
  float zi2 = __builtin_fmaf(zr1 + zr1, zi1, ci);
  bool  e2  = __builtin_fmaf(zr2, zr2, zi2 * zi2) > 4.0f;

  float t2  = __builtin_fmaf(-zi2, zi2, cr);
  float zr3 = __builtin_fmaf(zr2, zr2, t2);
  float zi3 = __builtin_fmaf(zr2 + zr2, zi2, ci);
  bool  e3  = __builtin_fmaf(zr3, zr3, zi3 * zi3) > 4.0f;

  float t3  = __builtin_fmaf(-zi3, zi3, cr);
  float zr4 = __builtin_fmaf(zr3, zr3, t3);
  float zi4 = __builtin_fmaf(zr3 + zr3, zi3, ci);
  bool  e4  = __builtin_fmaf(zr4, zr4, zi4 * zi4) > 4.0f;

  bool cyc = (fabsf(zr4 - zr3) < EPS) & (fabsf(zi4 - zi3) < EPS);
  zr = zr4; zi = zi4;

  if ((e1 | e2 | e3 | e4 | cyc) & alive) {   // rare path
    float f = 100.0f;                        // cycle-only default
    if (e4 & !cyc) f = fb + 4.0f;            // same-iter: cycle wins
    if (e3) f = fb + 3.0f;
    if (e2) f = fb + 2.0f;
    if (e1) f = fb + 1.0f;
    fin = fminf(f, 100.0f);                  // last-round overshoot clamp
    alive = false;
  }
}

// Closed-form bounded-orbit test: main cardioid + period-2 bulb.
// For these c the reference provably outputs exactly 100.0 (orbit stays in
// radius <2 so mag>4 never fires; either the 1-step detector fires -> 100,
// or the loop runs out -> 100). So we may retire them instantly.
__device__ __forceinline__ bool inside_main_regions(float cr, float ci) {
  float ci2 = ci * ci;
  float xq  = cr - 0.25f;
  float q   = __builtin_fmaf(xq, xq, ci2);
  bool card = q * (q + xq) < 0.25f * ci2;
  float xb  = cr + 1.0f;
  bool bulb = __builtin_fmaf(xb, xb, ci2) < 0.0625f;
  return card | bulb;
}

__global__ __launch_bounds__(TPB) void escape_partial(
    const float* __restrict__ crg, const float* __restrict__ cig,
    float* __restrict__ partial, int n) {
  __shared__ float4 q[EPB];
  __shared__ int scount;
  __shared__ float sm[4];

  const int tid  = threadIdx.x;
  const int lane = tid & 63;
  const int wid  = tid >> 6;
  const int blockBase = blockIdx.x * EPB;

  float nd = 0.0f;
  float eZr[4], eZi[4], eCr[4], eCi[4];
  bool  eAl[4];

  // ---- phase A: iters 1..R0 from z=0, float4 global loads ----
  const bool fullBlock = (blockBase + EPB) <= n;
  float4 vcr, vci;
  if (fullBlock) {
    vcr = reinterpret_cast<const float4*>(crg + blockBase)[tid];
    vci = reinterpret_cast<const float4*>(cig + blockBase)[tid];
  } else {
    int b = blockBase + 4 * tid;
    vcr.x = (b + 0 < n) ? crg[b + 0] : 9.0f;  vci.x = (b + 0 < n) ? cig[b + 0] : 9.0f;
    vcr.y = (b + 1 < n) ? crg[b + 1] : 9.0f;  vci.y = (b + 1 < n) ? cig[b + 1] : 9.0f;
    vcr.z = (b + 2 < n) ? crg[b + 2] : 9.0f;  vci.z = (b + 2 < n) ? cig[b + 2] : 9.0f;
    vcr.w = (b + 3 < n) ? crg[b + 3] : 9.0f;  vci.w = (b + 3 < n) ? cig[b + 3] : 9.0f;
  }
  const float crs[4] = {vcr.x, vcr.y, vcr.z, vcr.w};
  const float cis[4] = {vci.x, vci.y, vci.z, vci.w};
  const bool  vld[4] = {
    fullBlock || (blockBase + 4 * tid + 0 < n),
    fullBlock || (blockBase + 4 * tid + 1 < n),
    fullBlock || (blockBase + 4 * tid + 2 < n),
    fullBlock || (blockBase + 4 * tid + 3 < n)};

  #pragma unroll
  for (int k = 0; k < 4; ++k) {
    float c_r = crs[k], c_i = cis[k];
    bool inside = inside_main_regions(c_r, c_i) & vld[k];
    if (inside) nd += ND_INSET;            // provably iters == 100
    float zr = 0.0f, zi = 0.0f;            // body4 from z=0 reproduces z1=c
    float fin = 0.0f;
    bool alive = vld[k] & (!inside);
    body4(zr, zi, c_r, c_i, 0.0f, fin, alive);
    body4(zr, zi, c_r, c_i, 4.0f, fin, alive);
    body4(zr, zi, c_r, c_i, 8.0f, fin, alive);
    if (fin != 0.0f) nd += fabsf(fin - TARGET) * (1.0f / TARGET);
    eAl[k] = alive; eZr[k] = zr; eZi[k] = zi; eCr[k] = c_r; eCi[k] = c_i;
  }

  if (tid == 0) scount = 0;
  __syncthreads();
  #pragma unroll
  for (int k = 0; k < 4; ++k) {            // ballot-compact append into LDS queue
    unsigned long long bal = __ballot(eAl[k]);
    int cnt = __popcll(bal);
    if (cnt) {
      int wbase = 0;
      if (lane == 0) wbase = atomicAdd(&scount, cnt);
      wbase = __shfl(wbase, 0, 64);
      if (eAl[k]) {
        int pos = wbase + __popcll(bal & ((1ull << lane) - 1ull));
        q[pos] = make_float4(eZr[k], eZi[k], eCr[k], eCi[k]);
      }
    }
  }
  __syncthreads();
  int S = scount;
  int rot = 0;

  // ---- queue rounds: base = 12,24,...,96 (last overshoots to 108; clamped) ----
  for (int base = R0; base < MAXIT && S > 0; base += RSTEP) {
    rot = (rot + 64) & (TPB - 1);          // rotate partial-wave tail across SIMDs
    const int effTid = (tid + rot) & (TPB - 1);
    const float fb = (float)base;
    #pragma unroll
    for (int k = 0; k < 4; ++k) {
      eAl[k] = false;
      int j = k * TPB + effTid;
      if (j < S) {
        float4 e = q[j];
        float zr = e.x, zi = e.y, c_r = e.z, c_i = e.w;
        float fin = 0.0f;
        bool alive = true;
        body4(zr, zi, c_r, c_i, fb, fin, alive);
        body4(zr, zi, c_r, c_i, fb + 4.0f, fin, alive);
        body4(zr, zi, c_r, c_i, fb + 8.0f, fin, alive);
        if (fin != 0.0f) nd += fabsf(fin - TARGET) * (1.0f / TARGET);
        eAl[k] = alive; eZr[k] = zr; eZi[k] = zi; eCr[k] = c_r; eCi[k] = c_i;
      }
    }
    __syncthreads();                       // all queue reads done
    if (tid == 0) scount = 0;
    __syncthreads();
    #pragma unroll
    for (int k = 0; k < 4; ++k) {          // in-place re-compaction
      unsigned long long bal = __ballot(eAl[k]);
      int cnt = __popcll(bal);
      if (cnt) {
        int wbase = 0;
        if (lane == 0) wbase = atomicAdd(&scount, cnt);
        wbase = __shfl(wbase, 0, 64);
        if (eAl[k]) {
          int pos = wbase + __popcll(bal & ((1ull << lane) - 1ull));
          q[pos] = make_float4(eZr[k], eZi[k], eCr[k], eCi[k]);
        }
      }
    }
    __syncthreads();
    S = scount;
  }

  // ---- survivors (ran to >=100 without escape/cycle): iters = 100 ----
  {
    int mine = 0;
    #pragma unroll
    for (int k = 0; k < 4; ++k) if (k * TPB + tid < S) ++mine;
    nd += (float)mine * ND_INSET;
  }

  // ---- block reduce ----
  for (int off = 32; off > 0; off >>= 1) nd += __shfl_down(nd, off, 64);
  if (lane == 0) sm[wid] = nd;
  __syncthreads();
  if (tid == 0) partial[blockIdx.x] = sm[0] + sm[1] + sm[2] + sm[3];
}

// Single block, float4 reads of the partials.
__global__ __launch_bounds__(256) void reduce_final(
    const float* __restrict__ partial, int nparts,
    float* __restrict__ out, float scale) {
  float s = 0.0f;
  int n4 = nparts >> 2;
  const float4* p4 = reinterpret_cast<const float4*>(partial);
  for (int i = threadIdx.x; i < n4; i += 256) {
    float4 v = p4[i];
    s += (v.x + v.y) + (v.z + v.w);
  }
  for (int i = (n4 << 2) + threadIdx.x; i < nparts; i += 256) s += partial[i];
  for (int off = 32; off > 0; off >>= 1) s += __shfl_down(s, off, 64);
  __shared__ float sm[4];
  int lane = threadIdx.x & 63, wid = threadIdx.x >> 6;
  if (lane == 0) sm[wid] = s;
  __syncthreads();
  if (threadIdx.x == 0)
    out[0] = (sm[0] + sm[1] + sm[2] + sm[3]) * scale;
}

extern "C" void kernel_launch(void* const* d_in, const int* in_sizes, int n_in,
                              void* d_out, int out_size, void* d_ws, size_t ws_size,
                              hipStream_t stream) {
  const float* cr = (const float*)d_in[0];
  const float* ci = (const float*)d_in[1];
  int n = in_sizes[0];
  int blocks = (n + EPB - 1) / EPB;        // 8192 at N=8388608
  float* partial = (float*)d_ws;

  escape_partial<<<blocks, TPB, 0, stream>>>(cr, ci, partial, n);
  reduce_final<<<1, 256, 0, stream>>>(partial, blocks, (float*)d_out,
                                      WEIGHT / (float)n);
}